// Round 2
// baseline (22651.135 us; speedup 1.0000x reference)
//
#include <hip/hip_runtime.h>
#include <hip/hip_bf16.h>

typedef __hip_bfloat16 bf16;
typedef __attribute__((ext_vector_type(8))) short short8;
typedef __attribute__((ext_vector_type(4))) float f32x4;

#define NTHR 512
#define OUT_EMB 16777216ul   // T*L*B*IN = 256*2*64*512 (floats)

__device__ __forceinline__ float sgm(float x) { return 1.0f / (1.0f + expf(-x)); }

// D[MT*16,16] += A_f32[MT*16,kk] @ W_bf16[16,kk]^T.
// A is split in-register into hi(trunc)+lo(trunc of exact residual): err ~2^-14.
// A-operand layout: lane holds A[m=lane&15][k=quad*8+j]; W rows are output cols.
template<int MT>
__device__ __forceinline__ void wave_mma_f32a(const float* __restrict__ A, int lda,
                                              const bf16* __restrict__ W, int ldw,
                                              int kk, f32x4* acc, int lane) {
  const int m  = lane & 15;
  const int ko = (lane >> 4) * 8;
  const float* ap = A + (size_t)m * lda + ko;
  const short* wp = reinterpret_cast<const short*>(W) + (size_t)m * ldw + ko;
#pragma unroll 2
  for (int k = 0; k < kk; k += 32) {
    short8 b = *reinterpret_cast<const short8*>(wp + k);
#pragma unroll
    for (int mt = 0; mt < MT; ++mt) {
      const float* s = ap + (size_t)mt * 16 * lda + k;
      float4 x0 = *reinterpret_cast<const float4*>(s);
      float4 x1 = *reinterpret_cast<const float4*>(s + 4);
      float xs[8] = {x0.x, x0.y, x0.z, x0.w, x1.x, x1.y, x1.z, x1.w};
      short8 ahi, alo;
#pragma unroll
      for (int j = 0; j < 8; ++j) {
        unsigned u  = __builtin_bit_cast(unsigned, xs[j]);
        float hf    = __builtin_bit_cast(float, u & 0xFFFF0000u);
        unsigned ul = __builtin_bit_cast(unsigned, xs[j] - hf);
        ahi[j] = (short)(u >> 16);
        alo[j] = (short)(ul >> 16);
      }
      acc[mt] = __builtin_amdgcn_mfma_f32_16x16x32_bf16(ahi, b, acc[mt], 0, 0, 0);
      acc[mt] = __builtin_amdgcn_mfma_f32_16x16x32_bf16(alo, b, acc[mt], 0, 0, 0);
    }
  }
}

// ---------------- prologue kernels ----------------

__global__ void embed_kernel(const int* __restrict__ tgt, const float* __restrict__ table,
                             float* __restrict__ embout, unsigned* __restrict__ arrive) {
  const int row = blockIdx.x;                  // 0..16383 (t*64+b)
  const int tok = tgt[row];
  const uint2* src = reinterpret_cast<const uint2*>(table + (size_t)tok * 512);
  uint2* dst = reinterpret_cast<uint2*>(embout + (size_t)row * 512);
  dst[threadIdx.x] = src[threadIdx.x];         // 256 thr * 8B = 2048B = 512 f32
  if (row == 0 && threadIdx.x < 256) arrive[threadIdx.x] = 0;  // init grid barrier
}

__global__ void cvt_bf16_kernel(const float* __restrict__ src, bf16* __restrict__ dst, int n) {
  const int i = blockIdx.x * blockDim.x + threadIdx.x;
  if (i < n) dst[i] = __float2bfloat16(src[i]);
}

// wp0t_{hi,lo}[k][j] = split(Wp0[j][k])  (k<1024, j<512)
__global__ void transpose_kernel(const float* __restrict__ Wp0,
                                 bf16* __restrict__ thi, bf16* __restrict__ tlo) {
  const int k = blockIdx.x;                    // 0..1023
  for (int j = threadIdx.x; j < 512; j += blockDim.x) {
    const float x = Wp0[(size_t)j * 1024 + k];
    const bf16 h = __float2bfloat16(x);
    thi[(size_t)k * 512 + j] = h;
    tlo[(size_t)k * 512 + j] = __float2bfloat16(x - __bfloat162float(h));
  }
}

// wfub[n][k] = bf16( sum_j Wih1[n][j] * Wp0[j][k] )   (n<4096, k<1024)
__global__ void wfused_kernel(const float* __restrict__ Wih1, const bf16* __restrict__ thi,
                              const bf16* __restrict__ tlo, bf16* __restrict__ wfub) {
  const int bx = blockIdx.x & 63, by = blockIdx.x >> 6;
  const int wv = threadIdx.x >> 6, lane = threadIdx.x & 63;
  const f32x4 vz = {0.f, 0.f, 0.f, 0.f};
  f32x4 acc[4] = {vz, vz, vz, vz};
  wave_mma_f32a<4>(Wih1 + (size_t)bx * 64 * 512, 512,
                   thi + (size_t)(by * 64 + wv * 16) * 512, 512, 512, acc, lane);
  wave_mma_f32a<4>(Wih1 + (size_t)bx * 64 * 512, 512,
                   tlo + (size_t)(by * 64 + wv * 16) * 512, 512, 512, acc, lane);
  const int cc = lane & 15, qq = lane >> 4;
#pragma unroll
  for (int mt = 0; mt < 4; ++mt)
#pragma unroll
    for (int rg = 0; rg < 4; ++rg) {
      const int row = bx * 64 + mt * 16 + qq * 4 + rg;
      const int col = by * 64 + wv * 16 + cc;
      wfub[(size_t)row * 1024 + col] = __float2bfloat16(acc[mt][rg]);
    }
}

// bfx[n] = bih1[n] + bhh1[n] + sum_j Wih1[n][j]*bp0[j]   (f32)
__global__ void bfx_kernel(const float* __restrict__ Wih1, const float* __restrict__ bp0,
                           const float* __restrict__ bih1, const float* __restrict__ bhh1,
                           float* __restrict__ bfx) {
  const int n = blockIdx.x * blockDim.x + threadIdx.x;  // 4096
  float s = bih1[n] + bhh1[n];
  for (int j = 0; j < 512; ++j)
    s += Wih1[(size_t)n * 512 + j] * bp0[j];
  bfx[n] = s;
}

// ---------------- persistent recurrent kernel ----------------
// grid = 256 blocks x 512 threads (co-resident; ≥2 blocks/CU possible, still safe).
// Phase A(t): blocks [0,128)  : gates0 = pre0[t] + h0 @ Whh0^T -> elementwise -> h0'(t)
//             blocks [128,256): g1p = h1'(t-1) @ Whh1^T
// Phase B(t): blocks [0,128)  : gates1 = h0'(t) @ Wfused^T + g1p + bfx -> h1'(t)
//             blocks [128,160): out[t,0]  = h0'(t)  @ Wp0^T + bp0
//             blocks [160,192): out[t-1,1]= h1'(t-1)@ Wp1^T + bp1
//             blocks [192,256): pre0[t+1] = emb[t+1] @ Wih0^T + bih0 + bhh0
__global__ void __launch_bounds__(NTHR)
lstm_kernel(const float* __restrict__ h0in, const float* __restrict__ c0in,
            const bf16* __restrict__ wih0b, const bf16* __restrict__ whh0b,
            const float* __restrict__ bih0, const float* __restrict__ bhh0,
            const bf16* __restrict__ wp0b,  const float* __restrict__ bp0,
            const bf16* __restrict__ whh1b,
            const bf16* __restrict__ wp1b,  const float* __restrict__ bp1,
            float* __restrict__ out, unsigned* __restrict__ arrive,
            float* __restrict__ h0ws,   // [2][64*1024] f32 ping-pong
            float* __restrict__ h1ws,   // [2][64*1024] f32 ping-pong
            float* __restrict__ pre0,   // [2][64*4096] f32 ping-pong
            float* __restrict__ g1p,    // [64*4096] f32
            const bf16* __restrict__ wfub, const float* __restrict__ bfx)
{
  __shared__ float lds[8][64][17];
  const int bid = blockIdx.x, tid = threadIdx.x;
  const int wv = tid >> 6, lane = tid & 63;
  const int r = tid >> 4, c = tid & 15;          // epilogue element (r in 0..31)
  const int cg = bid >> 1, mh = bid & 1;         // roles for blocks < 128
  const int q = wv >> 1, kh = wv & 1;
  const float* embout = out + OUT_EMB;
  unsigned target = 0;
  float c0reg = 0.f, c1reg = 0.f;                // cell state lives in f32 registers
  const f32x4 vz = {0.f, 0.f, 0.f, 0.f};

  auto barrier = [&]() {
    ++target;
    __syncthreads();
    if (tid == 0)
      __hip_atomic_store(&arrive[bid], target, __ATOMIC_RELEASE, __HIP_MEMORY_SCOPE_AGENT);
    if (tid < 64) {
      for (;;) {
        bool ok = true;
#pragma unroll
        for (int j = 0; j < 4; ++j) {
          unsigned v = __hip_atomic_load(&arrive[tid * 4 + j], __ATOMIC_RELAXED,
                                         __HIP_MEMORY_SCOPE_AGENT);
          ok = ok && (v >= target);
        }
        if (ok) break;
        __builtin_amdgcn_s_sleep(2);
      }
    }
    __syncthreads();
    __builtin_amdgcn_fence(__ATOMIC_ACQUIRE, "agent");  // cross-XCD visibility
  };

  auto store_partials2 = [&](f32x4* acc, int rbase) {
    const int cc = lane & 15, qq = lane >> 4;
#pragma unroll
    for (int mt = 0; mt < 2; ++mt)
#pragma unroll
      for (int rg = 0; rg < 4; ++rg)
        lds[wv][rbase + mt * 16 + qq * 4 + rg][cc] = acc[mt][rg];
    __syncthreads();
  };

  // gates-style MMA for blocks < 128: waves (q=gate, kh=K-half), out tile [32,16]
  auto gates_mma = [&](const float* hsrc, const bf16* Wbig) {
    f32x4 acc[2] = {vz, vz};
    wave_mma_f32a<2>(hsrc + (size_t)mh * 32 * 1024 + kh * 512, 1024,
                     Wbig + (size_t)(q * 1024 + cg * 16) * 1024 + kh * 512, 1024,
                     512, acc, lane);
    store_partials2(acc, 0);
  };

  // projection: block covers cols cgp*16 of 512, full 64 rows; waves (kh4, mhw)
  auto proj_step = [&](const float* hsrc, const bf16* Wp_, const float* bp_,
                       float* dst, int cgp) {
    const int kh4 = wv >> 1, mhw = wv & 1;
    f32x4 acc[2] = {vz, vz};
    wave_mma_f32a<2>(hsrc + (size_t)mhw * 32 * 1024 + kh4 * 256, 1024,
                     Wp_ + (size_t)(cgp * 16) * 1024 + kh4 * 256, 1024,
                     256, acc, lane);
    store_partials2(acc, mhw * 32);
    float v0 = 0.f, v1 = 0.f;
#pragma unroll
    for (int k4 = 0; k4 < 4; ++k4) {
      v0 += lds[k4 * 2 + 0][r][c];
      v1 += lds[k4 * 2 + 1][r + 32][c];
    }
    const float bias = bp_[cgp * 16 + c];
    dst[(size_t)r * 512 + cgp * 16 + c]        = v0 + bias;
    dst[(size_t)(r + 32) * 512 + cgp * 16 + c] = v1 + bias;
  };

  // pre0 for timestep tt (blocks [192,256)): [64 rows, 64 cols] per block, K=512
  auto pre0_step = [&](int tt) {
    const int bb = bid - 192;
    const int cs = wv >> 1, k2 = wv & 1;
    f32x4 acc[4] = {vz, vz, vz, vz};
    wave_mma_f32a<4>(embout + (size_t)tt * (64 * 512) + k2 * 256, 512,
                     wih0b + (size_t)(bb * 64 + cs * 16) * 512 + k2 * 256, 512,
                     256, acc, lane);
    const int cc = lane & 15, qq = lane >> 4;
#pragma unroll
    for (int mt = 0; mt < 4; ++mt)
#pragma unroll
      for (int rg = 0; rg < 4; ++rg)
        lds[wv][mt * 16 + qq * 4 + rg][cc] = acc[mt][rg];
    __syncthreads();
    float* dst = pre0 + (size_t)(tt & 1) * (64 * 4096);
#pragma unroll
    for (int cs2 = 0; cs2 < 4; ++cs2) {
      const int n = bb * 64 + cs2 * 16 + c;
      const float bias = bih0[n] + bhh0[n];
      dst[(size_t)r * 4096 + n]        = lds[cs2 * 2][r][c]      + lds[cs2 * 2 + 1][r][c]      + bias;
      dst[(size_t)(r + 32) * 4096 + n] = lds[cs2 * 2][r + 32][c] + lds[cs2 * 2 + 1][r + 32][c] + bias;
    }
  };

  // g1p = h1'(t-1) @ Whh1^T  (blocks [128,256): [32 rows, 64 cols] per block)
  auto g1h_step = [&](int t) {
    const int idx = bid - 128;
    const int mh2 = idx & 1, cw = idx >> 1;
    const int cs = wv >> 1, k2 = wv & 1;
    f32x4 acc[2] = {vz, vz};
    wave_mma_f32a<2>(h1ws + (size_t)((t + 1) & 1) * (64 * 1024) + (size_t)mh2 * 32 * 1024 + k2 * 512, 1024,
                     whh1b + (size_t)(cw * 64 + cs * 16) * 1024 + k2 * 512, 1024,
                     512, acc, lane);
    store_partials2(acc, 0);
#pragma unroll
    for (int cs2 = 0; cs2 < 4; ++cs2)
      g1p[(size_t)(mh2 * 32 + r) * 4096 + cw * 64 + cs2 * 16 + c] =
          lds[cs2 * 2][r][c] + lds[cs2 * 2 + 1][r][c];
  };

  // ---------- prologue ----------
  if (bid < 128) {
    c0reg = c0in[(size_t)(mh * 32 + r) * 1024 + cg * 16 + c];
    c1reg = c0in[65536 + (size_t)(mh * 32 + r) * 1024 + cg * 16 + c];
  } else if (bid < 192) {
    const int rr = bid - 128;                       // copy initial h (f32)
    for (int j = tid; j < 1024; j += NTHR) {
      h0ws[(size_t)rr * 1024 + j] = h0in[(size_t)rr * 1024 + j];                     // buf0
      h1ws[64 * 1024 + (size_t)rr * 1024 + j] = h0in[65536 + (size_t)rr * 1024 + j]; // buf1
    }
  } else {
    pre0_step(0);
  }
  barrier();

  // ---------- recurrence ----------
  for (int t = 0; t < 256; ++t) {
    // phase A
    if (bid < 128) {
      gates_mma(h0ws + (size_t)(t & 1) * (64 * 1024), whh0b);
      float g[4];
      const float* p0 = pre0 + (size_t)(t & 1) * (64 * 4096) + (size_t)(mh * 32 + r) * 4096 + cg * 16 + c;
#pragma unroll
      for (int qi = 0; qi < 4; ++qi)
        g[qi] = lds[qi * 2][r][c] + lds[qi * 2 + 1][r][c] + p0[(size_t)qi * 1024];
      const float ii = sgm(g[0]), ff = sgm(g[1]), gg = tanhf(g[2]), oo = sgm(g[3]);
      c0reg = ff * c0reg + ii * gg;
      const float hv = oo * tanhf(c0reg);
      h0ws[(size_t)((t + 1) & 1) * (64 * 1024) + (size_t)(mh * 32 + r) * 1024 + cg * 16 + c] = hv;
    } else {
      g1h_step(t);
    }
    barrier();
    // phase B
    if (bid < 128) {
      gates_mma(h0ws + (size_t)((t + 1) & 1) * (64 * 1024), wfub);
      float g[4];
#pragma unroll
      for (int qi = 0; qi < 4; ++qi) {
        const int n = qi * 1024 + cg * 16 + c;
        g[qi] = lds[qi * 2][r][c] + lds[qi * 2 + 1][r][c] +
                g1p[(size_t)(mh * 32 + r) * 4096 + n] + bfx[n];
      }
      const float ii = sgm(g[0]), ff = sgm(g[1]), gg = tanhf(g[2]), oo = sgm(g[3]);
      c1reg = ff * c1reg + ii * gg;
      const float hv = oo * tanhf(c1reg);
      h1ws[(size_t)(t & 1) * (64 * 1024) + (size_t)(mh * 32 + r) * 1024 + cg * 16 + c] = hv;
    } else if (bid < 160) {
      proj_step(h0ws + (size_t)((t + 1) & 1) * (64 * 1024), wp0b, bp0,
                out + (size_t)(t * 2 + 0) * (64 * 512), bid - 128);
    } else if (bid < 192) {
      if (t > 0)
        proj_step(h1ws + (size_t)((t + 1) & 1) * (64 * 1024), wp1b, bp1,
                  out + (size_t)((t - 1) * 2 + 1) * (64 * 512), bid - 160);
    } else {
      if (t < 255) pre0_step(t + 1);
    }
    barrier();
  }
  // tail: out[255, 1]
  if (bid >= 160 && bid < 192) {
    proj_step(h1ws + (size_t)1 * (64 * 1024), wp1b, bp1,
              out + (size_t)(255 * 2 + 1) * (64 * 512), bid - 160);
  }
}

extern "C" void kernel_launch(void* const* d_in, const int* in_sizes, int n_in,
                              void* d_out, int out_size, void* d_ws, size_t ws_size,
                              hipStream_t stream) {
  (void)in_sizes; (void)n_in; (void)out_size; (void)ws_size;
  const int*   tgt  = (const int*)d_in[0];
  const float* h0in = (const float*)d_in[1];
  const float* c0in = (const float*)d_in[2];
  const float* table= (const float*)d_in[3];
  const float* Wih0 = (const float*)d_in[4];
  const float* Whh0 = (const float*)d_in[5];
  const float* bih0 = (const float*)d_in[6];
  const float* bhh0 = (const float*)d_in[7];
  const float* Wp0  = (const float*)d_in[8];
  const float* bp0  = (const float*)d_in[9];
  const float* Wih1 = (const float*)d_in[10];
  const float* Whh1 = (const float*)d_in[11];
  const float* bih1 = (const float*)d_in[12];
  const float* bhh1 = (const float*)d_in[13];
  const float* Wp1  = (const float*)d_in[14];
  const float* bp1  = (const float*)d_in[15];
  float* out = (float*)d_out;

  char* w = (char*)d_ws;
  size_t off = 0;
  auto alloc = [&](size_t bytes) { char* p = w + off; off += (bytes + 255) & ~255ul; return p; };
  unsigned* arrive = (unsigned*)alloc(1024);
  float* h0ws   = (float*)alloc(2 * 64 * 1024 * 4);
  float* h1ws   = (float*)alloc(2 * 64 * 1024 * 4);
  float* pre0   = (float*)alloc(2 * 64 * 4096 * 4);
  float* g1p    = (float*)alloc(64 * 4096 * 4);
  float* bfx    = (float*)alloc(4096 * 4);
  bf16* wp0thi  = (bf16*)alloc(1024 * 512 * 2);
  bf16* wp0tlo  = (bf16*)alloc(1024 * 512 * 2);
  bf16* wfub    = (bf16*)alloc(4096 * 1024 * 2);
  bf16* whh0b   = (bf16*)alloc(4096 * 1024 * 2);
  bf16* whh1b   = (bf16*)alloc(4096 * 1024 * 2);
  bf16* wih0b   = (bf16*)alloc(4096 * 512 * 2);
  bf16* wp0b    = (bf16*)alloc(512 * 1024 * 2);
  bf16* wp1b    = (bf16*)alloc(512 * 1024 * 2);

  embed_kernel<<<16384, 256, 0, stream>>>(tgt, table, out + OUT_EMB, arrive);
  cvt_bf16_kernel<<<16384, 256, 0, stream>>>(Whh0, whh0b, 4096 * 1024);
  cvt_bf16_kernel<<<16384, 256, 0, stream>>>(Whh1, whh1b, 4096 * 1024);
  cvt_bf16_kernel<<<8192, 256, 0, stream>>>(Wih0, wih0b, 4096 * 512);
  cvt_bf16_kernel<<<2048, 256, 0, stream>>>(Wp0, wp0b, 512 * 1024);
  cvt_bf16_kernel<<<2048, 256, 0, stream>>>(Wp1, wp1b, 512 * 1024);
  transpose_kernel<<<1024, 256, 0, stream>>>(Wp0, wp0thi, wp0tlo);
  wfused_kernel<<<1024, 256, 0, stream>>>(Wih1, wp0thi, wp0tlo, wfub);
  bfx_kernel<<<16, 256, 0, stream>>>(Wih1, bp0, bih1, bhh1, bfx);
  lstm_kernel<<<256, NTHR, 0, stream>>>(h0in, c0in, wih0b, whh0b, bih0, bhh0, wp0b, bp0,
                                        whh1b, wp1b, bp1, out, arrive, h0ws, h1ws,
                                        pre0, g1p, wfub, bfx);
}

// Round 3
// 16567.950 us; speedup vs baseline: 1.3672x; 1.3672x over previous
//
#include <hip/hip_runtime.h>
#include <hip/hip_bf16.h>

typedef __hip_bfloat16 bf16;
typedef __attribute__((ext_vector_type(8))) short short8;
typedef __attribute__((ext_vector_type(4))) float f32x4;

#define NTHR 512
#define OUT_EMB 16777216ul   // T*L*B*IN floats

__device__ __forceinline__ float sgm(float x) { return 1.0f / (1.0f + expf(-x)); }
__device__ __forceinline__ short8 ld8(const bf16* p) {
  return *reinterpret_cast<const short8*>(p);
}

// ---- plain bf16 wave MMA: D[MT*16,16] += A[MT*16,kk] @ W[16,kk]^T ----
template<int MT>
__device__ __forceinline__ void wave_mma_bf(const bf16* __restrict__ A, int lda,
                                            const bf16* __restrict__ W, int ldw,
                                            int kk, f32x4* acc, int lane) {
  const int m = lane & 15, ko = (lane >> 4) * 8;
  const bf16* ap = A + (size_t)m * lda + ko;
  const bf16* wp = W + (size_t)m * ldw + ko;
#pragma unroll 4
  for (int k = 0; k < kk; k += 32) {
    short8 b = ld8(wp + k);
#pragma unroll
    for (int mt = 0; mt < MT; ++mt) {
      short8 a = ld8(ap + (size_t)mt * 16 * lda + k);
      acc[mt] = __builtin_amdgcn_mfma_f32_16x16x32_bf16(a, b, acc[mt], 0, 0, 0);
    }
  }
}

// ---- f32-A split MMA (prologue wfused only) ----
template<int MT>
__device__ __forceinline__ void wave_mma_f32a(const float* __restrict__ A, int lda,
                                              const bf16* __restrict__ W, int ldw,
                                              int kk, f32x4* acc, int lane) {
  const int m = lane & 15, ko = (lane >> 4) * 8;
  const float* ap = A + (size_t)m * lda + ko;
  const short* wp = reinterpret_cast<const short*>(W) + (size_t)m * ldw + ko;
#pragma unroll 2
  for (int k = 0; k < kk; k += 32) {
    short8 b = *reinterpret_cast<const short8*>(wp + k);
#pragma unroll
    for (int mt = 0; mt < MT; ++mt) {
      const float* s = ap + (size_t)mt * 16 * lda + k;
      float4 x0 = *reinterpret_cast<const float4*>(s);
      float4 x1 = *reinterpret_cast<const float4*>(s + 4);
      float xs[8] = {x0.x, x0.y, x0.z, x0.w, x1.x, x1.y, x1.z, x1.w};
      short8 ahi, alo;
#pragma unroll
      for (int j = 0; j < 8; ++j) {
        unsigned u  = __builtin_bit_cast(unsigned, xs[j]);
        float hf    = __builtin_bit_cast(float, u & 0xFFFF0000u);
        unsigned ul = __builtin_bit_cast(unsigned, xs[j] - hf);
        ahi[j] = (short)(u >> 16);
        alo[j] = (short)(ul >> 16);
      }
      acc[mt] = __builtin_amdgcn_mfma_f32_16x16x32_bf16(ahi, b, acc[mt], 0, 0, 0);
      acc[mt] = __builtin_amdgcn_mfma_f32_16x16x32_bf16(alo, b, acc[mt], 0, 0, 0);
    }
  }
}

// ---------------- prologue kernels ----------------

__global__ void embed_kernel(const int* __restrict__ tgt, const float* __restrict__ table,
                             float* __restrict__ embout, bf16* __restrict__ embbf,
                             unsigned* __restrict__ arrive) {
  const int row = blockIdx.x;                  // t*64+b
  const int tok = tgt[row];
  const float2* src = reinterpret_cast<const float2*>(table + (size_t)tok * 512);
  float2 v = src[threadIdx.x];
  reinterpret_cast<float2*>(embout + (size_t)row * 512)[threadIdx.x] = v;
  ushort2 h;
  h.x = __builtin_bit_cast(unsigned short, __float2bfloat16(v.x));
  h.y = __builtin_bit_cast(unsigned short, __float2bfloat16(v.y));
  reinterpret_cast<ushort2*>(embbf + (size_t)row * 512)[threadIdx.x] = h;
  if (row == 0 && threadIdx.x < 256) arrive[threadIdx.x] = 0;
}

__global__ void cvt_bf16_kernel(const float* __restrict__ src, bf16* __restrict__ dst, int n) {
  const int i = blockIdx.x * blockDim.x + threadIdx.x;
  if (i < n) dst[i] = __float2bfloat16(src[i]);
}

__global__ void init_h_kernel(const float* __restrict__ h0in,
                              bf16* __restrict__ h0a, bf16* __restrict__ h1a) {
  const int idx = blockIdx.x * blockDim.x + threadIdx.x;   // 131072
  const int layer = idx >> 16, e = idx & 65535;
  bf16 v = __float2bfloat16(h0in[(size_t)layer * 65536 + e]);
  if (layer) h1a[e] = v; else h0a[e] = v;
}

// wp0t_{hi,lo}[k][j] = split(Wp0[j][k])
__global__ void transpose_kernel(const float* __restrict__ Wp0,
                                 bf16* __restrict__ thi, bf16* __restrict__ tlo) {
  const int k = blockIdx.x;
  for (int j = threadIdx.x; j < 512; j += blockDim.x) {
    const float x = Wp0[(size_t)j * 1024 + k];
    const bf16 h = __float2bfloat16(x);
    thi[(size_t)k * 512 + j] = h;
    tlo[(size_t)k * 512 + j] = __float2bfloat16(x - __bfloat162float(h));
  }
}

// wfub[n][k] = bf16( sum_j Wih1[n][j] * Wp0[j][k] )
__global__ void wfused_kernel(const float* __restrict__ Wih1, const bf16* __restrict__ thi,
                              const bf16* __restrict__ tlo, bf16* __restrict__ wfub) {
  const int bx = blockIdx.x & 63, by = blockIdx.x >> 6;
  const int wv = threadIdx.x >> 6, lane = threadIdx.x & 63;
  const f32x4 vz = {0.f, 0.f, 0.f, 0.f};
  f32x4 acc[4] = {vz, vz, vz, vz};
  wave_mma_f32a<4>(Wih1 + (size_t)bx * 64 * 512, 512,
                   thi + (size_t)(by * 64 + wv * 16) * 512, 512, 512, acc, lane);
  wave_mma_f32a<4>(Wih1 + (size_t)bx * 64 * 512, 512,
                   tlo + (size_t)(by * 64 + wv * 16) * 512, 512, 512, acc, lane);
  const int cc = lane & 15, qq = lane >> 4;
#pragma unroll
  for (int mt = 0; mt < 4; ++mt)
#pragma unroll
    for (int rg = 0; rg < 4; ++rg)
      wfub[(size_t)(bx * 64 + mt * 16 + qq * 4 + rg) * 1024 + by * 64 + wv * 16 + cc] =
          __float2bfloat16(acc[mt][rg]);
}

// bfx[n] = bih1[n] + bhh1[n] + sum_j Wih1[n][j]*bp0[j]
__global__ void bfx_kernel(const float* __restrict__ Wih1, const float* __restrict__ bp0,
                           const float* __restrict__ bih1, const float* __restrict__ bhh1,
                           float* __restrict__ bfx) {
  const int n = blockIdx.x * blockDim.x + threadIdx.x;
  float s = bih1[n] + bhh1[n];
  for (int j = 0; j < 512; ++j)
    s += Wih1[(size_t)n * 512 + j] * bp0[j];
  bfx[n] = s;
}

// pre0_all[R][n] = bf16( emb[R] @ Wih0[n]^T + bih0[n] + bhh0[n] ), R<16384, n<4096
__global__ void pre0_gemm_kernel(const bf16* __restrict__ embbf, const bf16* __restrict__ wih0b,
                                 const float* __restrict__ bih0, const float* __restrict__ bhh0,
                                 bf16* __restrict__ pre0) {
  const int ct = blockIdx.x & 63, rt = blockIdx.x >> 6;   // 64 col-tiles fastest
  const int wv = threadIdx.x >> 6, lane = threadIdx.x & 63;
  const f32x4 vz = {0.f, 0.f, 0.f, 0.f};
  f32x4 acc[4] = {vz, vz, vz, vz};
  wave_mma_bf<4>(embbf + (size_t)rt * 64 * 512, 512,
                 wih0b + (size_t)(ct * 64 + wv * 16) * 512, 512, 512, acc, lane);
  const int cc = lane & 15, qq = lane >> 4;
#pragma unroll
  for (int mt = 0; mt < 4; ++mt)
#pragma unroll
    for (int rg = 0; rg < 4; ++rg) {
      const int n = ct * 64 + wv * 16 + cc;
      const size_t R = (size_t)rt * 64 + mt * 16 + qq * 4 + rg;
      pre0[R * 4096 + n] = __float2bfloat16(acc[mt][rg] + bih0[n] + bhh0[n]);
    }
}

// out[t][l][brow][col] = h_l(t+1)[brow] @ Wp_l[col]^T + bp_l[col]
__global__ void proj_kernel(const bf16* __restrict__ h0a, const bf16* __restrict__ h1a,
                            const bf16* __restrict__ wp0b, const bf16* __restrict__ wp1b,
                            const float* __restrict__ bp0, const float* __restrict__ bp1,
                            float* __restrict__ out) {
  const int l = blockIdx.y;
  const bf16* ha = (l ? h1a : h0a) + 65536;          // rows R: addr R*1024
  const bf16* wp = l ? wp1b : wp0b;
  const float* bp = l ? bp1 : bp0;
  const int ct = blockIdx.x & 7, rt = blockIdx.x >> 3;
  const int wv = threadIdx.x >> 6, lane = threadIdx.x & 63;
  const f32x4 vz = {0.f, 0.f, 0.f, 0.f};
  f32x4 acc[4] = {vz, vz, vz, vz};
  wave_mma_bf<4>(ha + (size_t)rt * 64 * 1024, 1024,
                 wp + (size_t)(ct * 64 + wv * 16) * 1024, 1024, 1024, acc, lane);
  const int cc = lane & 15, qq = lane >> 4;
#pragma unroll
  for (int mt = 0; mt < 4; ++mt)
#pragma unroll
    for (int rg = 0; rg < 4; ++rg) {
      const int R = rt * 64 + mt * 16 + qq * 4 + rg;
      const int t = R >> 6, brow = R & 63;
      const int col = ct * 64 + wv * 16 + cc;
      out[((size_t)t * 2 + l) * 32768 + (size_t)brow * 512 + col] = acc[mt][rg] + bp[col];
    }
}

// ---------------- persistent recurrent kernel ----------------
// 256 blocks x 512 thr; block bid owns h-cols [bid*4, bid*4+4) of both layers.
// W slices: Whh0->VGPR, wfub->VGPR, Whh1->LDS. Weights never touch memory in-loop.
// Phase A: gates0 = pre0[t] + h0(t)@Whh0^T -> c0,h0'(t)
// Phase B: gates1 = h0'(t)@wfub^T + h1(t)@Whh1^T + bfx -> c1,h1'(t)
__global__ void __launch_bounds__(NTHR, 2)
lstm_kernel(const float* __restrict__ c0in,
            const bf16* __restrict__ whh0b, const bf16* __restrict__ wfub,
            const bf16* __restrict__ whh1b, const float* __restrict__ bfx,
            const bf16* __restrict__ pre0,  // [16384][4096] bf16
            bf16* __restrict__ h0a,         // [257][64][1024]
            bf16* __restrict__ h1a,         // [257][64][1024]
            unsigned* __restrict__ arrive)
{
  __shared__ float red[4][16][17];
  __shared__ short wl[16384];                // Whh1 slice [32ks][16col][32e] = 32 KB
  const int bid = blockIdx.x, tid = threadIdx.x;
  const int wv = tid >> 6, lane = tid & 63;
  const int rg = wv & 3, kh = wv >> 2;       // row-group, K-half
  const int cc = lane & 15, q = lane >> 4;
  const int nrow = (cc >> 2) * 1024 + bid * 4 + (cc & 3);  // gate-col index
  const f32x4 vz = {0.f, 0.f, 0.f, 0.f};
  unsigned target = 0;

  // --- preload weights ---
  short8 wfA[16], wfB[16];
#pragma unroll
  for (int ks = 0; ks < 16; ++ks) {
    wfA[ks] = ld8(whh0b + (size_t)nrow * 1024 + kh * 512 + ks * 32 + q * 8);
    wfB[ks] = ld8(wfub  + (size_t)nrow * 1024 + kh * 512 + ks * 32 + q * 8);
  }
  for (int e8 = tid * 8; e8 < 16384; e8 += NTHR * 8) {
    const int ks = e8 >> 9, col = (e8 >> 5) & 15, ko = e8 & 31;
    const int nr = (col >> 2) * 1024 + bid * 4 + (col & 3);
    *reinterpret_cast<short8*>(wl + e8) = ld8(whh1b + (size_t)nr * 1024 + ks * 32 + ko);
  }

  // --- per-thread state (threads 0..255: row=tid>>2, j2=tid&3) ---
  const int row = tid >> 2, j2 = tid & 3;
  float c0 = 0.f, c1 = 0.f, bfxr[4];
  if (tid < 256) {
    c0 = c0in[(size_t)row * 1024 + bid * 4 + j2];
    c1 = c0in[65536 + (size_t)row * 1024 + bid * 4 + j2];
#pragma unroll
    for (int gi = 0; gi < 4; ++gi) bfxr[gi] = bfx[gi * 1024 + bid * 4 + j2];
  }

  auto barrier = [&]() {
    ++target;
    __syncthreads();
    if (tid == 0)
      __hip_atomic_store(&arrive[bid], target, __ATOMIC_RELEASE, __HIP_MEMORY_SCOPE_AGENT);
    if (tid < 64) {
      for (;;) {
        bool ok = true;
#pragma unroll
        for (int j = 0; j < 4; ++j) {
          unsigned v = __hip_atomic_load(&arrive[tid * 4 + j], __ATOMIC_RELAXED,
                                         __HIP_MEMORY_SCOPE_AGENT);
          ok = ok && (v >= target);
        }
        if (ok) break;
        __builtin_amdgcn_s_sleep(1);
      }
    }
    __syncthreads();
    __builtin_amdgcn_fence(__ATOMIC_ACQUIRE, "agent");
  };

  // reduce 2 K-halves via LDS; leaves final preacts in red[rg][r][cc]
  auto reduce_red = [&](f32x4& acc) {
    if (kh == 1) {
#pragma unroll
      for (int r = 0; r < 4; ++r) red[rg][q * 4 + r][cc] = acc[r];
    }
    __syncthreads();
    if (kh == 0) {
#pragma unroll
      for (int r = 0; r < 4; ++r) red[rg][q * 4 + r][cc] = acc[r] + red[rg][q * 4 + r][cc];
    }
    __syncthreads();
  };

  barrier();   // weights/LDS loaded; also joins prologue ordering

  for (int t = 0; t < 256; ++t) {
    // ---- phase A: gates0 ----
    {
      f32x4 acc = vz;
      const bf16* ha = h0a + (size_t)t * 65536 + (size_t)(rg * 16 + cc) * 1024 + kh * 512 + q * 8;
#pragma unroll
      for (int ks = 0; ks < 16; ++ks)
        acc = __builtin_amdgcn_mfma_f32_16x16x32_bf16(ld8(ha + ks * 32), wfA[ks], acc, 0, 0, 0);
      reduce_red(acc);
      if (tid < 256) {
        const int rgE = row >> 4, r2 = row & 15;
        const bf16* pp = pre0 + (size_t)(t * 64 + row) * 4096 + bid * 4 + j2;
        float g[4];
#pragma unroll
        for (int gi = 0; gi < 4; ++gi)
          g[gi] = red[rgE][r2][gi * 4 + j2] + __bfloat162float(pp[gi * 1024]);
        const float ii = sgm(g[0]), ff = sgm(g[1]), gg = tanhf(g[2]), oo = sgm(g[3]);
        c0 = ff * c0 + ii * gg;
        h0a[(size_t)(t + 1) * 65536 + (size_t)row * 1024 + bid * 4 + j2] =
            __float2bfloat16(oo * tanhf(c0));
      }
    }
    barrier();
    // ---- phase B: gates1 ----
    {
      f32x4 acc = vz;
      const bf16* ha0 = h0a + (size_t)(t + 1) * 65536 + (size_t)(rg * 16 + cc) * 1024 + kh * 512 + q * 8;
      const bf16* ha1 = h1a + (size_t)t * 65536 + (size_t)(rg * 16 + cc) * 1024 + kh * 512 + q * 8;
      const short* wlw = wl + (kh * 16) * 512 + cc * 32 + q * 8;
#pragma unroll
      for (int ks = 0; ks < 16; ++ks)
        acc = __builtin_amdgcn_mfma_f32_16x16x32_bf16(ld8(ha0 + ks * 32), wfB[ks], acc, 0, 0, 0);
#pragma unroll
      for (int ks = 0; ks < 16; ++ks)
        acc = __builtin_amdgcn_mfma_f32_16x16x32_bf16(
            ld8(ha1 + ks * 32), *reinterpret_cast<const short8*>(wlw + ks * 512), acc, 0, 0, 0);
      reduce_red(acc);
      if (tid < 256) {
        const int rgE = row >> 4, r2 = row & 15;
        float g[4];
#pragma unroll
        for (int gi = 0; gi < 4; ++gi)
          g[gi] = red[rgE][r2][gi * 4 + j2] + bfxr[gi];
        const float ii = sgm(g[0]), ff = sgm(g[1]), gg = tanhf(g[2]), oo = sgm(g[3]);
        c1 = ff * c1 + ii * gg;
        h1a[(size_t)(t + 1) * 65536 + (size_t)row * 1024 + bid * 4 + j2] =
            __float2bfloat16(oo * tanhf(c1));
      }
    }
    barrier();
  }
}

extern "C" void kernel_launch(void* const* d_in, const int* in_sizes, int n_in,
                              void* d_out, int out_size, void* d_ws, size_t ws_size,
                              hipStream_t stream) {
  (void)in_sizes; (void)n_in; (void)out_size; (void)ws_size;
  const int*   tgt  = (const int*)d_in[0];
  const float* h0in = (const float*)d_in[1];
  const float* c0in = (const float*)d_in[2];
  const float* table= (const float*)d_in[3];
  const float* Wih0 = (const float*)d_in[4];
  const float* Whh0 = (const float*)d_in[5];
  const float* bih0 = (const float*)d_in[6];
  const float* bhh0 = (const float*)d_in[7];
  const float* Wp0  = (const float*)d_in[8];
  const float* bp0  = (const float*)d_in[9];
  const float* Wih1 = (const float*)d_in[10];
  const float* Whh1 = (const float*)d_in[11];
  const float* bih1 = (const float*)d_in[12];
  const float* bhh1 = (const float*)d_in[13];
  const float* Wp1  = (const float*)d_in[14];
  const float* bp1  = (const float*)d_in[15];
  float* out = (float*)d_out;

  char* w = (char*)d_ws;
  size_t off = 0;
  auto alloc = [&](size_t bytes) { char* p = w + off; off += (bytes + 255) & ~255ul; return p; };
  unsigned* arrive = (unsigned*)alloc(1024);
  float* bfx    = (float*)alloc(4096 * 4);
  bf16* embbf   = (bf16*)alloc(16384ul * 512 * 2);
  bf16* h0a     = (bf16*)alloc(257ul * 65536 * 2);
  bf16* h1a     = (bf16*)alloc(257ul * 65536 * 2);
  bf16* pre0    = (bf16*)alloc(16384ul * 4096 * 2);
  bf16* whh0b   = (bf16*)alloc(4096ul * 1024 * 2);
  bf16* whh1b   = (bf16*)alloc(4096ul * 1024 * 2);
  bf16* wih0b   = (bf16*)alloc(4096ul * 512 * 2);
  bf16* wp0b    = (bf16*)alloc(512ul * 1024 * 2);
  bf16* wp1b    = (bf16*)alloc(512ul * 1024 * 2);
  bf16* wfub    = (bf16*)alloc(4096ul * 1024 * 2);
  bf16* wp0thi  = (bf16*)alloc(1024ul * 512 * 2);
  bf16* wp0tlo  = (bf16*)alloc(1024ul * 512 * 2);

  embed_kernel<<<16384, 256, 0, stream>>>(tgt, table, out + OUT_EMB, embbf, arrive);
  cvt_bf16_kernel<<<16384, 256, 0, stream>>>(Whh0, whh0b, 4096 * 1024);
  cvt_bf16_kernel<<<16384, 256, 0, stream>>>(Whh1, whh1b, 4096 * 1024);
  cvt_bf16_kernel<<<8192, 256, 0, stream>>>(Wih0, wih0b, 4096 * 512);
  cvt_bf16_kernel<<<2048, 256, 0, stream>>>(Wp0, wp0b, 512 * 1024);
  cvt_bf16_kernel<<<2048, 256, 0, stream>>>(Wp1, wp1b, 512 * 1024);
  init_h_kernel<<<512, 256, 0, stream>>>(h0in, h0a, h1a);
  transpose_kernel<<<1024, 256, 0, stream>>>(Wp0, wp0thi, wp0tlo);
  wfused_kernel<<<1024, 256, 0, stream>>>(Wih1, wp0thi, wp0tlo, wfub);
  bfx_kernel<<<16, 256, 0, stream>>>(Wih1, bp0, bih1, bhh1, bfx);
  pre0_gemm_kernel<<<16384, 256, 0, stream>>>(embbf, wih0b, bih0, bhh0, pre0);
  lstm_kernel<<<256, NTHR, 0, stream>>>(c0in, whh0b, wfub, whh1b, bfx, pre0,
                                        h0a, h1a, arrive);
  dim3 pg(2048, 2);
  proj_kernel<<<pg, 256, 0, stream>>>(h0a, h1a, wp0b, wp1b, bp0, bp1, out);
}